// Round 11
// baseline (351.811 us; speedup 1.0000x reference)
//
#include <hip/hip_runtime.h>

typedef unsigned short ushort_t;
using bf16x8 = __attribute__((ext_vector_type(8))) short;
using u16x8  = __attribute__((ext_vector_type(8))) unsigned short;
using f32x4  = __attribute__((ext_vector_type(4))) float;

#define DEV static __device__ __forceinline__

DEV unsigned short f2bf(float f) {
  union { float f; unsigned u; } a; a.f = f;
  unsigned r = a.u + 0x7fffu + ((a.u >> 16) & 1u);
  return (unsigned short)(r >> 16);
}
DEV float bf2f(unsigned short u) {
  union { unsigned u; float f; } a; a.u = ((unsigned)u) << 16;
  return a.f;
}
DEV void load_lds16(const void* g, void* l) {
  __builtin_amdgcn_global_load_lds(
      (const __attribute__((address_space(1))) void*)g,
      (__attribute__((address_space(3))) void*)l, 16, 0, 0);
}

// ---------------------------------------------------------------- fused cast (x, wqkv, wproj)
__global__ __launch_bounds__(256) void cast3_kernel(
    const float* __restrict__ x, const float* __restrict__ wqkv,
    const float* __restrict__ wproj, ushort_t* __restrict__ xb,
    ushort_t* __restrict__ qb, ushort_t* __restrict__ pb) {
  int i = blockIdx.x * 256 + threadIdx.x;   // < 6291456 float4s
  const float4* s; ushort4* d; int off;
  if (i < 2097152)      { s = (const float4*)x;     d = (ushort4*)xb; off = i; }
  else if (i < 5242880) { s = (const float4*)wqkv;  d = (ushort4*)qb; off = i - 2097152; }
  else                  { s = (const float4*)wproj; d = (ushort4*)pb; off = i - 5242880; }
  float4 f = s[off];
  ushort4 o;
  o.x = f2bf(f.x); o.y = f2bf(f.y); o.z = f2bf(f.z); o.w = f2bf(f.w);
  d[off] = o;
}

// ---------------------------------------------------------------- rope tables
__global__ __launch_bounds__(256) void rope_tables_kernel(float* __restrict__ tab) {
  int idx = blockIdx.x * 256 + threadIdx.x;   // < 2048*64
  int s = idx >> 6, i = idx & 63;
  float rate = exp2f(-13.287712379549449f * ((float)(2 * i) * (1.0f / 128.0f)));
  float ang = (float)s * rate;
  tab[idx * 2]     = cosf(ang);
  tab[idx * 2 + 1] = sinf(ang);
}

// ---------------------------------------------------------------- balanced GEMM (proven 122us)
// C = A * B^T. A[M][K], B[N][K] bf16 row-major. Tile BM x BN, BK=32, 256 threads
// (4 waves, 2m x 2n; wave tile BM/2 x BN/2). Double-buffered LDS; one barrier per
// K-tile: stage(t+1) issued at top, __syncthreads (drains vmcnt) at bottom.
// Swizzle: 16B-slot ^= (row>>1)&3 on pre-swizzled source + reads.
template<int BM, int BN, int OUTF32>
__global__ __launch_bounds__(256, 2) void gemm_bal(
    const ushort_t* __restrict__ A, const ushort_t* __restrict__ Bm,
    void* __restrict__ C, int M, int N, int K) {
  constexpr int MF   = BM / 32;
  constexpr int NF   = BN / 32;
  constexpr int NCA  = BM / 64;
  constexpr int NCB  = BN / 64;
  constexpr int NC   = NCA + NCB;
  constexpr int ABY  = BM * 64;
  constexpr int BUFB = (BM + BN) * 64;
  __shared__ __align__(16) char lds[2 * BUFB];

  const int nby = M / BM;
  const int nwg = nby * (N / BN);
  const int orig = blockIdx.x;
  const int wgid = (orig & 7) * (nwg >> 3) + (orig >> 3);
  const int bm = (wgid % nby) * BM;
  const int bn = (wgid / nby) * BN;

  const int tid = threadIdx.x;
  const int lane = tid & 63;
  const int wave = tid >> 6;
  const int ql = lane & 15, lk = lane >> 4;
  const int wm = wave >> 1, wn = wave & 1;

  f32x4 acc[MF][NF];
#pragma unroll
  for (int m = 0; m < MF; ++m)
#pragma unroll
    for (int n = 0; n < NF; ++n) acc[m][n] = (f32x4){0.f, 0.f, 0.f, 0.f};

  const int rin  = tid >> 2;
  const int sswz = ((tid & 3) ^ ((rin >> 1) & 3)) * 16;
  const size_t rb = (size_t)K * 2;
  const char* src[NC];
#pragma unroll
  for (int c = 0; c < NCA; ++c)
    src[c] = (const char*)A + (size_t)(bm + c * 64 + rin) * rb + sswz;
#pragma unroll
  for (int c = 0; c < NCB; ++c)
    src[NCA + c] = (const char*)Bm + (size_t)(bn + c * 64 + rin) * rb + sswz;
  char* const ldsc = (char*)lds;
  const int dT = tid * 16;

  int aOff[MF], bOff[NF];
#pragma unroll
  for (int m = 0; m < MF; ++m) {
    const int r = wm * (BM / 2) + m * 16 + ql;
    aOff[m] = r * 64 + ((lk ^ ((r >> 1) & 3)) * 16);
  }
#pragma unroll
  for (int n = 0; n < NF; ++n) {
    const int r = wn * (BN / 2) + n * 16 + ql;
    bOff[n] = ABY + r * 64 + ((lk ^ ((r >> 1) & 3)) * 16);
  }

#define STAGE(BB, KT) do {                                   \
    char* d_ = ldsc + (BB) * BUFB + dT;                      \
    const size_t ko_ = (size_t)(KT) * 64;                    \
    _Pragma("unroll")                                        \
    for (int c = 0; c < NC; ++c)                             \
      load_lds16(src[c] + ko_, d_ + c * 4096);               \
  } while (0)
#define MFMA(a, b, c) __builtin_amdgcn_mfma_f32_16x16x32_bf16(a, b, c, 0, 0, 0)

  const int ns = K >> 5;
  STAGE(0, 0);
  __syncthreads();

  for (int t = 0; t < ns; ++t) {
    const int nk = (t + 1 < ns) ? t + 1 : t;
    STAGE((t + 1) & 1, nk);
    const char* sb = ldsc + (t & 1) * BUFB;
    bf16x8 bF[NF], aF[MF];
#pragma unroll
    for (int n = 0; n < NF; ++n) bF[n] = *(const bf16x8*)(sb + bOff[n]);
#pragma unroll
    for (int m = 0; m < MF; ++m) aF[m] = *(const bf16x8*)(sb + aOff[m]);
    __builtin_amdgcn_s_setprio(1);
#pragma unroll
    for (int m = 0; m < MF; ++m)
#pragma unroll
      for (int n = 0; n < NF; ++n)
        acc[m][n] = MFMA(aF[m], bF[n], acc[m][n]);
    __builtin_amdgcn_s_setprio(0);
    __syncthreads();
  }
#undef STAGE
#undef MFMA

#pragma unroll
  for (int m = 0; m < MF; ++m)
#pragma unroll
    for (int i = 0; i < 4; ++i) {
      const size_t row = (size_t)(bm + wm * (BM / 2) + m * 16 + lk * 4 + i);
#pragma unroll
      for (int n = 0; n < NF; ++n) {
        const size_t col = (size_t)(bn + wn * (BN / 2) + n * 16 + ql);
        float v = acc[m][n][i];
        if (OUTF32) ((float*)C)[row * (size_t)N + col] = v;
        else        ((ushort_t*)C)[row * (size_t)N + col] = f2bf(v);
      }
    }
}

// ---------------------------------------------------------------- RoPE + RMS + relayout (vectorized)
// 16 lanes per 128-elem row, 8 bf16 (4 rope pairs) per lane, 16B loads/stores.
// qkv (B,S,3E) -> q,k (B,H,S,D) rope+rms (scale*log2e folded into q); v -> vt (B,H,D,S).
__global__ __launch_bounds__(256) void rope_rms_kernel(
    const ushort_t* __restrict__ qkv, ushort_t* __restrict__ q,
    ushort_t* __restrict__ k, ushort_t* __restrict__ vt,
    const float* __restrict__ tab) {
  const int li  = threadIdx.x & 15;
  const int row = blockIdx.x * 16 + (threadIdx.x >> 4);  // (((b*S+s)*3)+which)*16+h
  const int h = row & 15;
  int t = row >> 4;
  const int which = t % 3; t /= 3;
  const int s = t & 2047;
  const int b = t >> 11;
  const size_t src = ((size_t)(b * 2048 + s)) * 6144 + which * 2048 + h * 128 + li * 8;
  u16x8 v = *(const u16x8*)&qkv[src];
  if (which == 2) {
    const size_t vbase = ((size_t)((b * 16 + h) * 128 + li * 8)) * 2048 + s;
#pragma unroll
    for (int j = 0; j < 8; ++j) vt[vbase + (size_t)j * 2048] = (ushort_t)v[j];
    return;
  }
  float lo[4], ro[4];
  float ss = 0.f;
#pragma unroll
  for (int j = 0; j < 4; ++j) {
    const float2 cs = *(const float2*)&tab[(s * 64 + li * 4 + j) * 2];
    const float a = bf2f((ushort_t)v[2 * j]);
    const float c = bf2f((ushort_t)v[2 * j + 1]);
    lo[j] = a * cs.x - c * cs.y;
    ro[j] = a * cs.y + c * cs.x;
    ss += lo[j] * lo[j] + ro[j] * ro[j];
  }
#pragma unroll
  for (int off = 1; off < 16; off <<= 1) ss += __shfl_xor(ss, off);
  float inv = rsqrtf(ss * (1.0f / 128.0f) + 1.1920928955078125e-07f);
  if (which == 0) inv *= 0.1275174398f;  // (1/sqrt(128)) * log2(e)
  ushort_t* dst = (which == 0) ? q : k;
  union { u16x8 v8; ushort_t u[8]; } o;
#pragma unroll
  for (int j = 0; j < 4; ++j) {
    o.u[2 * j]     = f2bf(lo[j] * inv);
    o.u[2 * j + 1] = f2bf(ro[j] * inv);
  }
  *(u16x8*)&dst[(((size_t)(b * 16 + h)) * 2048 + s) * 128 + li * 8] = o.v8;
}

// ---------------------------------------------------------------- flash attention (causal)
// (round-5 version, verbatim: grid (32,16), 4 waves x 16 q-rows, 2-pass in-block,
// KBLK=64, 64KB LDS -> 2 blocks/CU. Empirical best of 5 attention variants.)
__global__ __launch_bounds__(256) void attn_kernel(
    const ushort_t* __restrict__ Q, const ushort_t* __restrict__ K,
    const ushort_t* __restrict__ VT, ushort_t* __restrict__ Y) {
  __shared__ __align__(16) ushort_t sK[64 * 128];
  __shared__ __align__(16) ushort_t sV[128 * 64];
  const int bh = blockIdx.x;
  const int yp = blockIdx.y;
  const int wave = threadIdx.x >> 6, lane = threadIdx.x & 63;
  const int ql = lane & 15, lk = lane >> 4;
  const size_t hq = (size_t)bh * 2048 * 128;
  const int b = bh >> 4, h = bh & 15;

  const char* kB = (const char*)(K + hq);
  const char* vB = (const char*)(VT + hq);
  const char* kSrc[4]; char* kDst[4];
  const char* vSrc[4]; char* vDst[4];
#pragma unroll
  for (int t = 0; t < 4; ++t) {
    int r = wave * 16 + t * 4 + (lane >> 4);
    int kgr = r >> 4, lkr = (r >> 2) & 3, ir = r & 3;
    int rho = (kgr >> 1) * 32 + lkr * 8 + (kgr & 1) * 4 + ir;   // key-permutation
    kSrc[t] = kB + rho * 256 + (((lane & 15) * 16) ^ ((r & 7) << 4));
    kDst[t] = (char*)sK + (wave * 256 + t * 64 + lane) * 16;
    int d = wave * 32 + t * 8 + (lane >> 3);
    vSrc[t] = vB + (size_t)d * 4096 + (((lane & 7) * 16) ^ ((d & 7) << 4));
    vDst[t] = (char*)sV + (wave * 256 + t * 64 + lane) * 16;
  }

  for (int pass = 0; pass < 2; ++pass) {
    const int qt = pass ? (31 - yp) : yp;
    const int q = qt * 64 + wave * 16 + ql;

    bf16x8 qf[4];
#pragma unroll
    for (int ks = 0; ks < 4; ++ks)
      qf[ks] = *(const bf16x8*)&Q[hq + (size_t)q * 128 + ks * 32 + lk * 8];

    f32x4 acc[8];
#pragma unroll
    for (int g = 0; g < 8; ++g) acc[g] = (f32x4){0.f, 0.f, 0.f, 0.f};
    float mrow = -3.0e38f, lsum = 0.f;

    for (int kt = 0; kt <= qt; ++kt) {
#pragma unroll
      for (int t = 0; t < 4; ++t) {
        load_lds16(kSrc[t] + (size_t)kt * 16384, kDst[t]);
        load_lds16(vSrc[t] + kt * 128, vDst[t]);
      }
      __syncthreads();

      // S^T = K . Q^T   (lane&15 = q-row; keys permuted by rho)
      f32x4 st[4];
#pragma unroll
      for (int kg = 0; kg < 4; ++kg) st[kg] = (f32x4){0.f, 0.f, 0.f, 0.f};
#pragma unroll
      for (int kg = 0; kg < 4; ++kg) {
        const int row = kg * 16 + ql;
        const int rswz = (row & 7) << 4;
#pragma unroll
        for (int ks = 0; ks < 4; ++ks) {
          bf16x8 kf = *(const bf16x8*)((const char*)sK + row * 256 + ((ks * 64 + lk * 16) ^ rswz));
          st[kg] = __builtin_amdgcn_mfma_f32_16x16x32_bf16(kf, qf[ks], st[kg], 0, 0, 0);
        }
      }
      float sv[4][4]; float mp = -3.0e38f;
#pragma unroll
      for (int kg = 0; kg < 4; ++kg) {
        const int kl = ((kg >> 1) << 5) + lk * 8 + ((kg & 1) << 2);
#pragma unroll
        for (int i = 0; i < 4; ++i) {
          const int key = kt * 64 + kl + i;
          float v = (key <= q) ? st[kg][i] : -3.0e38f;
          sv[kg][i] = v;
          mp = fmaxf(mp, v);
        }
      }
      mp = fmaxf(mp, __shfl_xor(mp, 16));
      mp = fmaxf(mp, __shfl_xor(mp, 32));
      const float mn = fmaxf(mrow, mp);
      const float corr = exp2f(mrow - mn);
      mrow = mn;
      float p[4][4]; float rs = 0.f;
#pragma unroll
      for (int kg = 0; kg < 4; ++kg)
#pragma unroll
        for (int i = 0; i < 4; ++i) {
          float e = exp2f(sv[kg][i] - mn);
          p[kg][i] = e; rs += e;
        }
      rs += __shfl_xor(rs, 16);
      rs += __shfl_xor(rs, 32);
      lsum = lsum * corr + rs;
#pragma unroll
      for (int g = 0; g < 8; ++g)
#pragma unroll
        for (int i = 0; i < 4; ++i) acc[g][i] *= corr;
      bf16x8 pb[2];
#pragma unroll
      for (int c = 0; c < 2; ++c) {
        union { bf16x8 v; ushort_t u[8]; } pk;
#pragma unroll
        for (int j = 0; j < 8; ++j) pk.u[j] = f2bf(p[2 * c + (j >> 2)][j & 3]);
        pb[c] = pk.v;
      }
#pragma unroll
      for (int dg = 0; dg < 8; ++dg) {
        const int d = dg * 16 + ql;
        const int dswz = (d & 7) << 4;
#pragma unroll
        for (int c = 0; c < 2; ++c) {
          bf16x8 vf = *(const bf16x8*)((const char*)sV + d * 128 + ((c * 64 + lk * 16) ^ dswz));
          acc[dg] = __builtin_amdgcn_mfma_f32_16x16x32_bf16(vf, pb[c], acc[dg], 0, 0, 0);
        }
      }
      __syncthreads();
    }

    const float inv = 1.0f / lsum;
    const size_t orow = ((size_t)(b * 2048 + q)) * 2048 + h * 128;
#pragma unroll
    for (int dg = 0; dg < 8; ++dg) {
      ushort4 o;
      o.x = f2bf(acc[dg][0] * inv);
      o.y = f2bf(acc[dg][1] * inv);
      o.z = f2bf(acc[dg][2] * inv);
      o.w = f2bf(acc[dg][3] * inv);
      *(ushort4*)&Y[orow + dg * 16 + lk * 4] = o;
    }
  }
}

// ---------------------------------------------------------------- launch
extern "C" void kernel_launch(void* const* d_in, const int* in_sizes, int n_in,
                              void* d_out, int out_size, void* d_ws, size_t ws_size,
                              hipStream_t stream) {
  const float* x     = (const float*)d_in[0];
  const float* wqkv  = (const float*)d_in[1];
  const float* wproj = (const float*)d_in[2];
  float* out = (float*)d_out;
  char* ws = (char*)d_ws;

  ushort_t* x_bf     = (ushort_t*)(ws);                // 16,777,216
  ushort_t* wqkv_bf  = (ushort_t*)(ws + 16777216);     // 25,165,824
  ushort_t* wproj_bf = (ushort_t*)(ws + 41943040);     //  8,388,608
  ushort_t* qkv_bf   = (ushort_t*)(ws + 50331648);     // 50,331,648 (reused as y)
  ushort_t* q_bf     = (ushort_t*)(ws + 100663296);    // 16,777,216
  ushort_t* k_bf     = (ushort_t*)(ws + 117440512);    // 16,777,216
  ushort_t* vt_bf    = (ushort_t*)(ws + 134217728);    // 16,777,216 (B,H,D,S)
  float*    tab      = (float*)(ws + 150994944);       //  1,048,576
  if (ws_size < 152043520u) return;

  cast3_kernel<<<24576, 256, 0, stream>>>(x, wqkv, wproj, x_bf, wqkv_bf, wproj_bf);
  rope_tables_kernel<<<512, 256, 0, stream>>>(tab);

  // qkv = x @ w_qkv^T  (4096 x 6144 x 2048): tile 256x128, grid 768 = 3/CU exact
  gemm_bal<256, 128, 0><<<768, 256, 0, stream>>>(x_bf, wqkv_bf, qkv_bf, 4096, 6144, 2048);

  rope_rms_kernel<<<12288, 256, 0, stream>>>(qkv_bf, q_bf, k_bf, vt_bf, tab);

  attn_kernel<<<dim3(32, 16), 256, 0, stream>>>(q_bf, k_bf, vt_bf, qkv_bf /* y */);

  // out = y @ w_proj^T  (4096 x 2048 x 2048): tile 128x128, grid 512 = 2/CU resident
  gemm_bal<128, 128, 1><<<512, 256, 0, stream>>>(qkv_bf, wproj_bf, out, 4096, 2048, 2048);
}

// Round 12
// 311.629 us; speedup vs baseline: 1.1289x; 1.1289x over previous
//
#include <hip/hip_runtime.h>

typedef unsigned short ushort_t;
using bf16x8 = __attribute__((ext_vector_type(8))) short;
using f32x4  = __attribute__((ext_vector_type(4))) float;

#define DEV static __device__ __forceinline__

DEV unsigned short f2bf(float f) {
  union { float f; unsigned u; } a; a.f = f;
  unsigned r = a.u + 0x7fffu + ((a.u >> 16) & 1u);
  return (unsigned short)(r >> 16);
}
DEV float bf2f(unsigned short u) {
  union { unsigned u; float f; } a; a.u = ((unsigned)u) << 16;
  return a.f;
}
DEV void load_lds16(const void* g, void* l) {
  __builtin_amdgcn_global_load_lds(
      (const __attribute__((address_space(1))) void*)g,
      (__attribute__((address_space(3))) void*)l, 16, 0, 0);
}

// ---------------------------------------------------------------- fused cast (x, wqkv, wproj)
__global__ __launch_bounds__(256) void cast3_kernel(
    const float* __restrict__ x, const float* __restrict__ wqkv,
    const float* __restrict__ wproj, ushort_t* __restrict__ xb,
    ushort_t* __restrict__ qb, ushort_t* __restrict__ pb) {
  int i = blockIdx.x * 256 + threadIdx.x;   // < 6291456 float4s
  const float4* s; ushort4* d; int off;
  if (i < 2097152)      { s = (const float4*)x;     d = (ushort4*)xb; off = i; }
  else if (i < 5242880) { s = (const float4*)wqkv;  d = (ushort4*)qb; off = i - 2097152; }
  else                  { s = (const float4*)wproj; d = (ushort4*)pb; off = i - 5242880; }
  float4 f = s[off];
  ushort4 o;
  o.x = f2bf(f.x); o.y = f2bf(f.y); o.z = f2bf(f.z); o.w = f2bf(f.w);
  d[off] = o;
}

// ---------------------------------------------------------------- rope tables
__global__ __launch_bounds__(256) void rope_tables_kernel(float* __restrict__ tab) {
  int idx = blockIdx.x * 256 + threadIdx.x;   // < 2048*64
  int s = idx >> 6, i = idx & 63;
  float rate = exp2f(-13.287712379549449f * ((float)(2 * i) * (1.0f / 128.0f)));
  float ang = (float)s * rate;
  tab[idx * 2]     = cosf(ang);
  tab[idx * 2 + 1] = sinf(ang);
}

// ---------------------------------------------------------------- balanced GEMM (proven 122us)
// C = A * B^T. A[M][K], B[N][K] bf16 row-major. Tile BM x BN, BK=32, 256 threads
// (4 waves, 2m x 2n; wave tile BM/2 x BN/2). Double-buffered LDS; one barrier per
// K-tile: stage(t+1) issued at top, __syncthreads (drains vmcnt) at bottom.
// Swizzle: 16B-slot ^= (row>>1)&3 on pre-swizzled source + reads.
template<int BM, int BN, int OUTF32>
__global__ __launch_bounds__(256, 2) void gemm_bal(
    const ushort_t* __restrict__ A, const ushort_t* __restrict__ Bm,
    void* __restrict__ C, int M, int N, int K) {
  constexpr int MF   = BM / 32;
  constexpr int NF   = BN / 32;
  constexpr int NCA  = BM / 64;
  constexpr int NCB  = BN / 64;
  constexpr int NC   = NCA + NCB;
  constexpr int ABY  = BM * 64;
  constexpr int BUFB = (BM + BN) * 64;
  __shared__ __align__(16) char lds[2 * BUFB];

  const int nby = M / BM;
  const int nwg = nby * (N / BN);
  const int orig = blockIdx.x;
  const int wgid = (orig & 7) * (nwg >> 3) + (orig >> 3);
  const int bm = (wgid % nby) * BM;
  const int bn = (wgid / nby) * BN;

  const int tid = threadIdx.x;
  const int lane = tid & 63;
  const int wave = tid >> 6;
  const int ql = lane & 15, lk = lane >> 4;
  const int wm = wave >> 1, wn = wave & 1;

  f32x4 acc[MF][NF];
#pragma unroll
  for (int m = 0; m < MF; ++m)
#pragma unroll
    for (int n = 0; n < NF; ++n) acc[m][n] = (f32x4){0.f, 0.f, 0.f, 0.f};

  const int rin  = tid >> 2;
  const int sswz = ((tid & 3) ^ ((rin >> 1) & 3)) * 16;
  const size_t rb = (size_t)K * 2;
  const char* src[NC];
#pragma unroll
  for (int c = 0; c < NCA; ++c)
    src[c] = (const char*)A + (size_t)(bm + c * 64 + rin) * rb + sswz;
#pragma unroll
  for (int c = 0; c < NCB; ++c)
    src[NCA + c] = (const char*)Bm + (size_t)(bn + c * 64 + rin) * rb + sswz;
  char* const ldsc = (char*)lds;
  const int dT = tid * 16;

  int aOff[MF], bOff[NF];
#pragma unroll
  for (int m = 0; m < MF; ++m) {
    const int r = wm * (BM / 2) + m * 16 + ql;
    aOff[m] = r * 64 + ((lk ^ ((r >> 1) & 3)) * 16);
  }
#pragma unroll
  for (int n = 0; n < NF; ++n) {
    const int r = wn * (BN / 2) + n * 16 + ql;
    bOff[n] = ABY + r * 64 + ((lk ^ ((r >> 1) & 3)) * 16);
  }

#define STAGE(BB, KT) do {                                   \
    char* d_ = ldsc + (BB) * BUFB + dT;                      \
    const size_t ko_ = (size_t)(KT) * 64;                    \
    _Pragma("unroll")                                        \
    for (int c = 0; c < NC; ++c)                             \
      load_lds16(src[c] + ko_, d_ + c * 4096);               \
  } while (0)
#define MFMA(a, b, c) __builtin_amdgcn_mfma_f32_16x16x32_bf16(a, b, c, 0, 0, 0)

  const int ns = K >> 5;
  STAGE(0, 0);
  __syncthreads();

  for (int t = 0; t < ns; ++t) {
    const int nk = (t + 1 < ns) ? t + 1 : t;
    STAGE((t + 1) & 1, nk);
    const char* sb = ldsc + (t & 1) * BUFB;
    bf16x8 bF[NF], aF[MF];
#pragma unroll
    for (int n = 0; n < NF; ++n) bF[n] = *(const bf16x8*)(sb + bOff[n]);
#pragma unroll
    for (int m = 0; m < MF; ++m) aF[m] = *(const bf16x8*)(sb + aOff[m]);
    __builtin_amdgcn_s_setprio(1);
#pragma unroll
    for (int m = 0; m < MF; ++m)
#pragma unroll
      for (int n = 0; n < NF; ++n)
        acc[m][n] = MFMA(aF[m], bF[n], acc[m][n]);
    __builtin_amdgcn_s_setprio(0);
    __syncthreads();
  }
#undef STAGE
#undef MFMA

#pragma unroll
  for (int m = 0; m < MF; ++m)
#pragma unroll
    for (int i = 0; i < 4; ++i) {
      const size_t row = (size_t)(bm + wm * (BM / 2) + m * 16 + lk * 4 + i);
#pragma unroll
      for (int n = 0; n < NF; ++n) {
        const size_t col = (size_t)(bn + wn * (BN / 2) + n * 16 + ql);
        float v = acc[m][n][i];
        if (OUTF32) ((float*)C)[row * (size_t)N + col] = v;
        else        ((ushort_t*)C)[row * (size_t)N + col] = f2bf(v);
      }
    }
}

// ---------------------------------------------------------------- RoPE + RMS + relayout (scalar, proven)
__global__ __launch_bounds__(256) void rope_rms_kernel(
    const ushort_t* __restrict__ qkv, ushort_t* __restrict__ q,
    ushort_t* __restrict__ k, ushort_t* __restrict__ vt,
    const float* __restrict__ tab) {
  const int lane = threadIdx.x & 63;
  const int row  = blockIdx.x * 4 + (threadIdx.x >> 6);  // (((b*S+s)*3)+which)*16+h
  const int h = row & 15;
  int t = row >> 4;
  const int which = t % 3; t /= 3;
  const int s = t & 2047;
  const int b = t >> 11;
  const size_t src = ((size_t)(b * 2048 + s)) * 6144 + which * 2048 + h * 128 + lane * 2;
  ushort2 xv = *(const ushort2*)&qkv[src];
  if (which == 2) {
    size_t vbase = ((size_t)((b * 16 + h) * 128 + lane * 2)) * 2048 + s;
    vt[vbase]        = xv.x;
    vt[vbase + 2048] = xv.y;
    return;
  }
  float lo = bf2f(xv.x), ro = bf2f(xv.y);
  const float2 cs = *(const float2*)&tab[(s * 64 + lane) * 2];
  float l2 = lo * cs.x - ro * cs.y;
  float r2 = lo * cs.y + ro * cs.x;
  float ss = l2 * l2 + r2 * r2;
#pragma unroll
  for (int off = 1; off < 64; off <<= 1) ss += __shfl_xor(ss, off);
  float inv = rsqrtf(ss * (1.0f / 128.0f) + 1.1920928955078125e-07f);
  if (which == 0) inv *= 0.1275174398f;  // (1/sqrt(128)) * log2(e)
  lo = l2 * inv; ro = r2 * inv;
  ushort_t* dst = (which == 0) ? q : k;
  ushort2 o; o.x = f2bf(lo); o.y = f2bf(ro);
  *(ushort2*)&dst[(((size_t)(b * 16 + h)) * 2048 + s) * 128 + lane * 2] = o;
}

// ---------------------------------------------------------------- flash attention (causal)
// r5 structure (grid (32,16), 4 waves x 16 q-rows, 2-pass in-block pairing, KBLK=64)
// + TRUE double-buffer: stage kt+1 into buf^1 BEFORE computing kt, one barrier/iter.
// The barrier's vmcnt drain now lands loads issued ~one compute-phase earlier ->
// HBM latency hidden. LDS 64KB -> still 2 blocks/CU. Cross-pass prefetch at pass-0 tail.
__global__ __launch_bounds__(256) void attn_kernel(
    const ushort_t* __restrict__ Q, const ushort_t* __restrict__ K,
    const ushort_t* __restrict__ VT, ushort_t* __restrict__ Y) {
  __shared__ __align__(16) ushort_t sK[2][64 * 128];
  __shared__ __align__(16) ushort_t sV[2][128 * 64];
  const int bh = blockIdx.x;
  const int yp = blockIdx.y;
  const int wave = threadIdx.x >> 6, lane = threadIdx.x & 63;
  const int ql = lane & 15, lk = lane >> 4;
  const size_t hq = (size_t)bh * 2048 * 128;
  const int b = bh >> 4, h = bh & 15;

  const char* kB = (const char*)(K + hq);
  const char* vB = (const char*)(VT + hq);
  const char* kSrc[4]; char* kDst[4];
  const char* vSrc[4]; char* vDst[4];
#pragma unroll
  for (int t = 0; t < 4; ++t) {
    int r = wave * 16 + t * 4 + (lane >> 4);
    int kgr = r >> 4, lkr = (r >> 2) & 3, ir = r & 3;
    int rho = (kgr >> 1) * 32 + lkr * 8 + (kgr & 1) * 4 + ir;   // key-permutation
    kSrc[t] = kB + rho * 256 + (((lane & 15) * 16) ^ ((r & 7) << 4));
    kDst[t] = (char*)sK + (wave * 256 + t * 64 + lane) * 16;
    int d = wave * 32 + t * 8 + (lane >> 3);
    vSrc[t] = vB + (size_t)d * 4096 + (((lane & 7) * 16) ^ ((d & 7) << 4));
    vDst[t] = (char*)sV + (wave * 256 + t * 64 + lane) * 16;
  }

#define STAGEKV(KT, BB) do {                                                  \
    _Pragma("unroll")                                                        \
    for (int t_ = 0; t_ < 4; ++t_) {                                         \
      load_lds16(kSrc[t_] + (size_t)(KT) * 16384, kDst[t_] + (BB) * 16384);  \
      load_lds16(vSrc[t_] + (KT) * 128,           vDst[t_] + (BB) * 16384);  \
    }                                                                        \
  } while (0)

  int buf = 0;
  STAGEKV(0, 0);
  __syncthreads();

  for (int pass = 0; pass < 2; ++pass) {
    const int qt = pass ? (31 - yp) : yp;
    const int q = qt * 64 + wave * 16 + ql;

    bf16x8 qf[4];
#pragma unroll
    for (int ks = 0; ks < 4; ++ks)
      qf[ks] = *(const bf16x8*)&Q[hq + (size_t)q * 128 + ks * 32 + lk * 8];

    f32x4 acc[8];
#pragma unroll
    for (int g = 0; g < 8; ++g) acc[g] = (f32x4){0.f, 0.f, 0.f, 0.f};
    float mrow = -3.0e38f, lsum = 0.f;

    for (int kt = 0; kt <= qt; ++kt) {
      // prefetch: next kt, or pass-1's kt=0 at pass-0 tail (kt=0 dummy at pass-1 tail)
      const int nk = (kt < qt) ? kt + 1 : 0;
      STAGEKV(nk, buf ^ 1);
      const char* sKb = (const char*)sK + buf * 16384;
      const char* sVb = (const char*)sV + buf * 16384;

      // S^T = K . Q^T   (lane&15 = q-row; keys permuted by rho)
      f32x4 st[4];
#pragma unroll
      for (int kg = 0; kg < 4; ++kg) st[kg] = (f32x4){0.f, 0.f, 0.f, 0.f};
#pragma unroll
      for (int kg = 0; kg < 4; ++kg) {
        const int row = kg * 16 + ql;
        const int rswz = (row & 7) << 4;
#pragma unroll
        for (int ks = 0; ks < 4; ++ks) {
          bf16x8 kf = *(const bf16x8*)(sKb + row * 256 + ((ks * 64 + lk * 16) ^ rswz));
          st[kg] = __builtin_amdgcn_mfma_f32_16x16x32_bf16(kf, qf[ks], st[kg], 0, 0, 0);
        }
      }
      float sv[4][4]; float mp = -3.0e38f;
#pragma unroll
      for (int kg = 0; kg < 4; ++kg) {
        const int kl = ((kg >> 1) << 5) + lk * 8 + ((kg & 1) << 2);
#pragma unroll
        for (int i = 0; i < 4; ++i) {
          const int key = kt * 64 + kl + i;
          float v = (key <= q) ? st[kg][i] : -3.0e38f;
          sv[kg][i] = v;
          mp = fmaxf(mp, v);
        }
      }
      mp = fmaxf(mp, __shfl_xor(mp, 16));
      mp = fmaxf(mp, __shfl_xor(mp, 32));
      const float mn = fmaxf(mrow, mp);
      const float corr = exp2f(mrow - mn);
      mrow = mn;
      float p[4][4]; float rs = 0.f;
#pragma unroll
      for (int kg = 0; kg < 4; ++kg)
#pragma unroll
        for (int i = 0; i < 4; ++i) {
          float e = exp2f(sv[kg][i] - mn);
          p[kg][i] = e; rs += e;
        }
      rs += __shfl_xor(rs, 16);
      rs += __shfl_xor(rs, 32);
      lsum = lsum * corr + rs;
#pragma unroll
      for (int g = 0; g < 8; ++g)
#pragma unroll
        for (int i = 0; i < 4; ++i) acc[g][i] *= corr;
      bf16x8 pb[2];
#pragma unroll
      for (int c = 0; c < 2; ++c) {
        union { bf16x8 v; ushort_t u[8]; } pk;
#pragma unroll
        for (int j = 0; j < 8; ++j) pk.u[j] = f2bf(p[2 * c + (j >> 2)][j & 3]);
        pb[c] = pk.v;
      }
#pragma unroll
      for (int dg = 0; dg < 8; ++dg) {
        const int d = dg * 16 + ql;
        const int dswz = (d & 7) << 4;
#pragma unroll
        for (int c = 0; c < 2; ++c) {
          bf16x8 vf = *(const bf16x8*)(sVb + d * 128 + ((c * 64 + lk * 16) ^ dswz));
          acc[dg] = __builtin_amdgcn_mfma_f32_16x16x32_bf16(vf, pb[c], acc[dg], 0, 0, 0);
        }
      }
      __syncthreads();   // drains vmcnt: prefetched tile landed; fences LDS reuse
      buf ^= 1;
    }

    const float inv = 1.0f / lsum;
    const size_t orow = ((size_t)(b * 2048 + q)) * 2048 + h * 128;
#pragma unroll
    for (int dg = 0; dg < 8; ++dg) {
      ushort4 o;
      o.x = f2bf(acc[dg][0] * inv);
      o.y = f2bf(acc[dg][1] * inv);
      o.z = f2bf(acc[dg][2] * inv);
      o.w = f2bf(acc[dg][3] * inv);
      *(ushort4*)&Y[orow + dg * 16 + lk * 4] = o;
    }
  }
#undef STAGEKV
}

// ---------------------------------------------------------------- launch
extern "C" void kernel_launch(void* const* d_in, const int* in_sizes, int n_in,
                              void* d_out, int out_size, void* d_ws, size_t ws_size,
                              hipStream_t stream) {
  const float* x     = (const float*)d_in[0];
  const float* wqkv  = (const float*)d_in[1];
  const float* wproj = (const float*)d_in[2];
  float* out = (float*)d_out;
  char* ws = (char*)d_ws;

  ushort_t* x_bf     = (ushort_t*)(ws);                // 16,777,216
  ushort_t* wqkv_bf  = (ushort_t*)(ws + 16777216);     // 25,165,824
  ushort_t* wproj_bf = (ushort_t*)(ws + 41943040);     //  8,388,608
  ushort_t* qkv_bf   = (ushort_t*)(ws + 50331648);     // 50,331,648 (reused as y)
  ushort_t* q_bf     = (ushort_t*)(ws + 100663296);    // 16,777,216
  ushort_t* k_bf     = (ushort_t*)(ws + 117440512);    // 16,777,216
  ushort_t* vt_bf    = (ushort_t*)(ws + 134217728);    // 16,777,216 (B,H,D,S)
  float*    tab      = (float*)(ws + 150994944);       //  1,048,576
  if (ws_size < 152043520u) return;

  cast3_kernel<<<24576, 256, 0, stream>>>(x, wqkv, wproj, x_bf, wqkv_bf, wproj_bf);
  rope_tables_kernel<<<512, 256, 0, stream>>>(tab);

  // qkv = x @ w_qkv^T  (4096 x 6144 x 2048): tile 256x128, grid 768 = 3/CU exact
  gemm_bal<256, 128, 0><<<768, 256, 0, stream>>>(x_bf, wqkv_bf, qkv_bf, 4096, 6144, 2048);

  rope_rms_kernel<<<49152, 256, 0, stream>>>(qkv_bf, q_bf, k_bf, vt_bf, tab);

  attn_kernel<<<dim3(32, 16), 256, 0, stream>>>(q_bf, k_bf, vt_bf, qkv_bf /* y */);

  // out = y @ w_proj^T  (4096 x 2048 x 2048): tile 128x128, grid 512 = 2/CU resident
  gemm_bal<128, 128, 1><<<512, 256, 0, stream>>>(qkv_bf, wproj_bf, out, 4096, 2048, 2048);
}